// Round 2
// baseline (272.427 us; speedup 1.0000x reference)
//
#include <hip/hip_runtime.h>
#include <hip/hip_bf16.h>
#include <stdint.h>

typedef __attribute__((ext_vector_type(8))) short bf16x8;
typedef __attribute__((ext_vector_type(4))) float f32x4;
typedef __attribute__((address_space(1))) const void g_void;
typedef __attribute__((address_space(3))) void l_void;

#define NB 16
#define NC 256
#define NHW 4096
#define NK 2304  // 9*256

// ---------- prep: x NCHW f32 -> xt NHWC bf16 (tile transpose) ----------
__global__ __launch_bounds__(256) void prep_xt(const float* __restrict__ x,
                                               __hip_bfloat16* __restrict__ xt) {
  __shared__ float tile[64][65];
  const int b = blockIdx.z;
  const int cb = blockIdx.y << 6;
  const int pb = blockIdx.x << 6;
  const float* xs = x + ((size_t)(b * NC + cb) << 12) + pb;
#pragma unroll
  for (int k = 0; k < 16; ++k) {
    int idx = threadIdx.x + (k << 8);
    int c = idx >> 6, p = idx & 63;
    tile[p][c] = xs[((size_t)c << 12) + p];
  }
  __syncthreads();
  __hip_bfloat16* xd = xt + ((size_t)(b * NHW + pb) << 8) + cb;
#pragma unroll
  for (int k = 0; k < 16; ++k) {
    int idx = threadIdx.x + (k << 8);
    int p = idx >> 6, c = idx & 63;
    xd[(p << 8) + c] = __float2bfloat16(tile[p][c]);
  }
}

// ---------- prep: kernel [b][co][ci][3][3] f32 -> kt [b][co][s][ci] bf16 ----------
__global__ __launch_bounds__(256) void prep_kt(const float* __restrict__ kin,
                                               __hip_bfloat16* __restrict__ kt) {
  const size_t base = (size_t)blockIdx.x * NK;  // blockIdx.x = b*256+co
  const int ci = threadIdx.x;
  float v[9];
#pragma unroll
  for (int s = 0; s < 9; ++s) v[s] = kin[base + ci * 9 + s];
#pragma unroll
  for (int s = 0; s < 9; ++s) kt[base + (s << 8) + ci] = __float2bfloat16(v[s]);
}

__global__ void zero_zp(float* zp) { zp[threadIdx.x] = 0.f; }

// ---------- implicit-GEMM conv, 128x128 tile, BK=32, global_load_lds staging ----------
// PASS 1: A=image(M=pixel), B=kernel(N=co), out = ht bf16 NHWC (relu)
// PASS 2: A=kernel(M=co), B=image(N=pixel), out = fp32 NCHW (x + .., relu)
template <int PASS>
__global__ __launch_bounds__(256) void conv_gemm(
    const __hip_bfloat16* __restrict__ img,  // [B][4096][256] bf16 (xt or ht)
    const __hip_bfloat16* __restrict__ kt,   // [B][256][2304] bf16
    const float* __restrict__ xres,          // pass2 residual (NCHW f32)
    const __hip_bfloat16* __restrict__ zp,   // 256B zero page
    void* __restrict__ outp) {
  __shared__ short Is[4096];  // 128 pixel-rows x 32 ci, 16B chunks XOR-swizzled
  __shared__ short Ks[4096];  // 128 co-rows    x 32 k

  const int tid = threadIdx.x;
  const int lane = tid & 63;
  const int wid = tid >> 6;
  const int wm = wid >> 1;
  const int wn = wid & 1;

  // XCD-affine swizzle: XCD x (= orig&7) owns logical blocks [128x, 128x+128)
  // => each XCD processes 2 complete samples (3.2MB working set fits 4MB L2).
  const int orig = blockIdx.x;
  const int g = ((orig & 7) << 7) + (orig >> 3);
  const int b = g >> 6;
  const int t = g & 63;
  const int pix_tile = t & 31;
  const int co_tile = t >> 5;
  const int pbase = pix_tile << 7;
  const int cobase = co_tile << 7;

  const __hip_bfloat16* imgb = img + ((size_t)b << 20);
  const __hip_bfloat16* ktb = kt + (size_t)b * NC * NK;

  // staging geometry: instruction i (0,1), wave wid covers tile rows
  // m = i*64 + wid*16 + (lane>>2); HW writes LDS slot lane&3 of row m.
  // Pre-swizzle the global chunk so LDS content matches the swizzled reads:
  // stored-at-slot s must hold chunk s ^ ((m>>1)&3).
  int h0[2], w0[2], schA[2];
  const __hip_bfloat16* krow[2];
#pragma unroll
  for (int i = 0; i < 2; ++i) {
    const int m = (i << 6) + (wid << 4) + (lane >> 2);
    const int sch = (lane & 3) ^ ((m >> 1) & 3);
    schA[i] = sch;
    const int p = pbase + m;
    h0[i] = p >> 6;
    w0[i] = p & 63;
    krow[i] = ktb + (size_t)(cobase + m) * NK + (sch << 3);
  }

  // fragment read offsets (shorts): row = wX*64+i*16+(lane&15), chunk = lane>>4
  int aoff[4], boff[4];
#pragma unroll
  for (int i = 0; i < 4; ++i) {
    int ma = (wm << 6) + (i << 4) + (lane & 15);
    aoff[i] = (ma << 5) + ((((lane >> 4) ^ ((ma >> 1) & 3))) << 3);
    int nb = (wn << 6) + (i << 4) + (lane & 15);
    boff[i] = (nb << 5) + ((((lane >> 4) ^ ((nb >> 1) & 3))) << 3);
  }

  const short* At = (PASS == 1) ? Is : Ks;
  const short* Bt = (PASS == 1) ? Ks : Is;

  f32x4 acc[4][4];
#pragma unroll
  for (int i = 0; i < 4; ++i)
#pragma unroll
    for (int j = 0; j < 4; ++j) acc[i][j] = (f32x4){0.f, 0.f, 0.f, 0.f};

#pragma unroll 1
  for (int step = 0; step < 72; ++step) {
    const int s = step >> 3;            // 0..8 = (kh,kw), uniform (SALU)
    const int dh = s / 3 - 1;
    const int dw = s % 3 - 1;
    const int cb = (step & 7) << 5;     // ci block base
#pragma unroll
    for (int i = 0; i < 2; ++i) {
      const int h = h0[i] + dh;
      const int w = w0[i] + dw;
      const bool ok = ((unsigned)h < 64u) && ((unsigned)w < 64u);
      const __hip_bfloat16* srcA =
          ok ? imgb + (((size_t)((h << 6) + w)) << 8) + (cb + (schA[i] << 3))
             : zp + (schA[i] << 3);
      __builtin_amdgcn_global_load_lds((g_void*)srcA,
                                       (l_void*)&Is[((i << 2) + wid) << 9], 16, 0, 0);
      const __hip_bfloat16* srcB = krow[i] + (step << 5);
      __builtin_amdgcn_global_load_lds((g_void*)srcB,
                                       (l_void*)&Ks[((i << 2) + wid) << 9], 16, 0, 0);
    }
    __syncthreads();  // compiler drains vmcnt(0) before s_barrier -> LDS ready

    bf16x8 fa[4], fb[4];
#pragma unroll
    for (int i = 0; i < 4; ++i) fa[i] = *(const bf16x8*)(At + aoff[i]);
#pragma unroll
    for (int j = 0; j < 4; ++j) fb[j] = *(const bf16x8*)(Bt + boff[j]);
#pragma unroll
    for (int i = 0; i < 4; ++i)
#pragma unroll
      for (int j = 0; j < 4; ++j)
        acc[i][j] = __builtin_amdgcn_mfma_f32_16x16x32_bf16(fa[i], fb[j], acc[i][j], 0, 0, 0);
    __syncthreads();  // protect LDS before next stage overwrites
  }

  const int lg = lane >> 4;
  const int ln = lane & 15;
  if (PASS == 1) {
    __hip_bfloat16* ho = (__hip_bfloat16*)outp;
#pragma unroll
    for (int i = 0; i < 4; ++i)
#pragma unroll
      for (int j = 0; j < 4; ++j)
#pragma unroll
        for (int r = 0; r < 4; ++r) {
          int pixel = pbase + (wm << 6) + (i << 4) + (lg << 2) + r;
          int co = cobase + (wn << 6) + (j << 4) + ln;
          float v = acc[i][j][r];
          v = v > 0.f ? v : 0.f;
          ho[((size_t)(b * NHW + pixel) << 8) + co] = __float2bfloat16(v);
        }
  } else {
    float* oo = (float*)outp;
#pragma unroll
    for (int i = 0; i < 4; ++i)
#pragma unroll
      for (int j = 0; j < 4; ++j)
#pragma unroll
        for (int r = 0; r < 4; ++r) {
          int co = cobase + (wm << 6) + (i << 4) + (lg << 2) + r;
          int pixel = pbase + (wn << 6) + (j << 4) + ln;
          size_t idx = ((size_t)(b * NC + co) << 12) + pixel;
          float v = acc[i][j][r] + xres[idx];
          oo[idx] = v > 0.f ? v : 0.f;
        }
  }
}

extern "C" void kernel_launch(void* const* d_in, const int* in_sizes, int n_in,
                              void* d_out, int out_size, void* d_ws, size_t ws_size,
                              hipStream_t stream) {
  const float* x = (const float*)d_in[0];
  const float* k1 = (const float*)d_in[1];
  const float* k2 = (const float*)d_in[2];

  // ws layout: xt (32MB) | ht (32MB) | kt (18MB, reused k1 then k2) | zp (256B)
  __hip_bfloat16* xt = (__hip_bfloat16*)d_ws;
  __hip_bfloat16* ht = xt + (size_t)NB * NHW * NC;
  __hip_bfloat16* kt = ht + (size_t)NB * NHW * NC;
  float* zp = (float*)(kt + (size_t)NB * NC * NK);

  zero_zp<<<dim3(1), 64, 0, stream>>>(zp);
  prep_xt<<<dim3(64, 4, NB), 256, 0, stream>>>(x, xt);
  prep_kt<<<dim3(NB * NC), 256, 0, stream>>>(k1, kt);
  conv_gemm<1><<<dim3(1024), 256, 0, stream>>>(xt, kt, nullptr, (const __hip_bfloat16*)zp, (void*)ht);
  prep_kt<<<dim3(NB * NC), 256, 0, stream>>>(k2, kt);
  conv_gemm<2><<<dim3(1024), 256, 0, stream>>>(ht, kt, x, (const __hip_bfloat16*)zp, d_out);
}

// Round 3
// 250.011 us; speedup vs baseline: 1.0897x; 1.0897x over previous
//
#include <hip/hip_runtime.h>
#include <hip/hip_bf16.h>
#include <stdint.h>

typedef __attribute__((ext_vector_type(8))) short bf16x8;
typedef __attribute__((ext_vector_type(4))) float f32x4;
typedef __attribute__((address_space(1))) const void g_void;
typedef __attribute__((address_space(3))) void l_void;

#define NB 16
#define NC 256
#define NHW 4096
#define NK 2304  // 9*256
#define NT 72    // K-tiles of 32

// ---------- prep: x NCHW f32 -> xt NHWC bf16 (tile transpose) ----------
__global__ __launch_bounds__(256) void prep_xt(const float* __restrict__ x,
                                               __hip_bfloat16* __restrict__ xt) {
  __shared__ float tile[64][65];
  const int b = blockIdx.z;
  const int cb = blockIdx.y << 6;
  const int pb = blockIdx.x << 6;
  const float* xs = x + ((size_t)(b * NC + cb) << 12) + pb;
#pragma unroll
  for (int k = 0; k < 16; ++k) {
    int idx = threadIdx.x + (k << 8);
    int c = idx >> 6, p = idx & 63;
    tile[p][c] = xs[((size_t)c << 12) + p];
  }
  __syncthreads();
  __hip_bfloat16* xd = xt + ((size_t)(b * NHW + pb) << 8) + cb;
#pragma unroll
  for (int k = 0; k < 16; ++k) {
    int idx = threadIdx.x + (k << 8);
    int p = idx >> 6, c = idx & 63;
    xd[(p << 8) + c] = __float2bfloat16(tile[p][c]);
  }
}

// ---------- prep: kernel [b][co][ci][3][3] f32 -> kt [b][co][s][ci] bf16 ----------
__global__ __launch_bounds__(256) void prep_kt(const float* __restrict__ kin,
                                               __hip_bfloat16* __restrict__ kt) {
  const size_t base = (size_t)blockIdx.x * NK;  // blockIdx.x = b*256+co
  const int ci = threadIdx.x;
  float v[9];
#pragma unroll
  for (int s = 0; s < 9; ++s) v[s] = kin[base + ci * 9 + s];
#pragma unroll
  for (int s = 0; s < 9; ++s) kt[base + (s << 8) + ci] = __float2bfloat16(v[s]);
}

__global__ void zero_zp(float* zp) { zp[threadIdx.x] = 0.f; }

// ---------- implicit-GEMM conv, 256x256 tile, BK=32, 4-deep pipelined LDS ----------
// PASS 1: A=image(M=pixel), B=kernel(N=co), out = ht bf16 NHWC (relu)
// PASS 2: A=kernel(M=co), B=image(N=pixel), out = fp32 NCHW (x + .., relu)
template <int PASS>
__global__ __launch_bounds__(512, 2) void conv_gemm(
    const __hip_bfloat16* __restrict__ img,  // [B][4096][256] bf16 (xt or ht)
    const __hip_bfloat16* __restrict__ kt,   // [B][256][2304] bf16
    const float* __restrict__ xres,          // pass2 residual (NCHW f32)
    const __hip_bfloat16* __restrict__ zp,   // 256B zero page
    void* __restrict__ outp) {
  // 4-deep circular buffers: tile t lives in buf[t&3]; stage t+3 during t.
  __shared__ short Ais[4][8192];  // image tile [256 pix][32 k], 64B rows, swizzled
  __shared__ short Kis[4][8192];  // kernel tile [256 co ][32 k]

  const int tid = threadIdx.x;
  const int lane = tid & 63;
  const int wid = tid >> 6;  // 0..7
  const int wm = wid >> 2;   // 0..1  (M half: 128 rows)
  const int wn = wid & 3;    // 0..3  (N quarter: 64 cols)

  // XCD-affine: XCD x owns logical blocks [32x,32x+32) = samples 2x,2x+1
  const int orig = blockIdx.x;
  const int g = ((orig & 7) << 5) + (orig >> 3);
  const int b = g >> 4;
  const int ptile = g & 15;
  const int pbase = ptile << 8;  // 256 pixels per tile

  const __hip_bfloat16* imgb = img + ((size_t)b << 20);
  const __hip_bfloat16* ktb = kt + (size_t)b * NC * NK;

  // ---- staging geometry: per thread 2 instrs per operand tile.
  // instr i: wave writes rows ((i*8+wid)*16 .. +16), lane -> row +(lane>>2),
  // slot lane&3. Stored slot s of row r holds data chunk s ^ ((r>>1)&3);
  // with 16-row-aligned bases this is chunk = (lane&3) ^ ((lane>>3)&3).
  const int c = (lane & 3) ^ ((lane >> 3) & 3);
  int hh[2], ww[2];
  const __hip_bfloat16* imgp[2];
  const __hip_bfloat16* ktp[2];
#pragma unroll
  for (int i = 0; i < 2; ++i) {
    const int m = (((i << 3) + wid) << 4) + (lane >> 2);  // tile row 0..255
    const int p = pbase + m;
    hh[i] = p >> 6;
    ww[i] = p & 63;
    imgp[i] = imgb + ((size_t)p << 8) + (c << 3);
    ktp[i] = ktb + (size_t)m * NK + (c << 3);
  }

  // ---- fragment read offsets (shorts): row m, chunk lane>>4, swizzled
  int aoff[8], boff[4];
#pragma unroll
  for (int i = 0; i < 8; ++i) {
    const int m = (wm << 7) + (i << 4) + (lane & 15);
    aoff[i] = (m << 5) + ((((lane >> 4) ^ ((m >> 1) & 3))) << 3);
  }
#pragma unroll
  for (int j = 0; j < 4; ++j) {
    const int n = (wn << 6) + (j << 4) + (lane & 15);
    boff[j] = (n << 5) + ((((lane >> 4) ^ ((n >> 1) & 3))) << 3);
  }

  f32x4 acc[8][4];
#pragma unroll
  for (int i = 0; i < 8; ++i)
#pragma unroll
    for (int j = 0; j < 4; ++j) acc[i][j] = (f32x4){0.f, 0.f, 0.f, 0.f};

  auto stage = [&](int tn) {
    const int buf = tn & 3;
    const int s = tn >> 3;  // 0..8 = (kh,kw)
    const int dh = s / 3 - 1;
    const int dw = s % 3 - 1;
    const int ci0 = (tn & 7) << 5;
    const int doff = (((dh << 6) + dw) << 8) + ci0;  // image offset (shorts)
    const int kof = (s << 8) + ci0;                  // kernel k offset
    const bool dummy = tn >= NT;  // tail: keep vmcnt counting uniform
#pragma unroll
    for (int i = 0; i < 2; ++i) {
      const int h = hh[i] + dh;
      const int w = ww[i] + dw;
      const bool ok = !dummy && ((unsigned)h < 64u) && ((unsigned)w < 64u);
      const __hip_bfloat16* sa = ok ? imgp[i] + doff : zp;
      __builtin_amdgcn_global_load_lds((g_void*)sa,
                                       (l_void*)&Ais[buf][(((i << 3) + wid) << 9)], 16, 0, 0);
      const __hip_bfloat16* sb = dummy ? zp : ktp[i] + kof;
      __builtin_amdgcn_global_load_lds((g_void*)sb,
                                       (l_void*)&Kis[buf][(((i << 3) + wid) << 9)], 16, 0, 0);
    }
  };

  // prologue: 3 tiles in flight
  stage(0);
  stage(1);
  stage(2);

#pragma unroll 1
  for (int t = 0; t < NT; ++t) {
    // 12 loads outstanding (tiles t,t+1,t+2); wait oldest 4 (= tile t).
    asm volatile("s_waitcnt vmcnt(8)" ::: "memory");
    __builtin_amdgcn_s_barrier();  // raw barrier: no vmcnt(0) drain
    stage(t + 3);                  // writes buf[(t+3)&3] (dead since t-1)

    const short* At = (PASS == 1) ? Ais[t & 3] : Kis[t & 3];
    const short* Bt = (PASS == 1) ? Kis[t & 3] : Ais[t & 3];
    bf16x8 fa[8], fb[4];
#pragma unroll
    for (int i = 0; i < 8; ++i) fa[i] = *(const bf16x8*)(At + aoff[i]);
#pragma unroll
    for (int j = 0; j < 4; ++j) fb[j] = *(const bf16x8*)(Bt + boff[j]);
    __builtin_amdgcn_s_setprio(1);
#pragma unroll
    for (int i = 0; i < 8; ++i)
#pragma unroll
      for (int j = 0; j < 4; ++j)
        acc[i][j] = __builtin_amdgcn_mfma_f32_16x16x32_bf16(fa[i], fb[j], acc[i][j], 0, 0, 0);
    __builtin_amdgcn_s_setprio(0);
  }
  __builtin_amdgcn_sched_barrier(0);  // keep epilogue VMEM out of the loop

  const int lg = lane >> 4;
  const int ln = lane & 15;
  if (PASS == 1) {
    __hip_bfloat16* ho = (__hip_bfloat16*)outp;
#pragma unroll
    for (int i = 0; i < 8; ++i)
#pragma unroll
      for (int j = 0; j < 4; ++j)
#pragma unroll
        for (int r = 0; r < 4; ++r) {
          int pixel = pbase + (wm << 7) + (i << 4) + (lg << 2) + r;
          int co = (wn << 6) + (j << 4) + ln;
          float v = acc[i][j][r];
          v = v > 0.f ? v : 0.f;
          ho[((size_t)(b * NHW + pixel) << 8) + co] = __float2bfloat16(v);
        }
  } else {
    float* oo = (float*)outp;
#pragma unroll
    for (int i = 0; i < 8; ++i)
#pragma unroll
      for (int j = 0; j < 4; ++j)
#pragma unroll
        for (int r = 0; r < 4; ++r) {
          int co = (wm << 7) + (i << 4) + (lg << 2) + r;
          int pixel = pbase + (wn << 6) + (j << 4) + ln;
          size_t idx = ((size_t)(b * NC + co) << 12) + pixel;
          float v = acc[i][j][r] + xres[idx];
          oo[idx] = v > 0.f ? v : 0.f;
        }
  }
}

extern "C" void kernel_launch(void* const* d_in, const int* in_sizes, int n_in,
                              void* d_out, int out_size, void* d_ws, size_t ws_size,
                              hipStream_t stream) {
  const float* x = (const float*)d_in[0];
  const float* k1 = (const float*)d_in[1];
  const float* k2 = (const float*)d_in[2];

  // ws layout: xt (32MB) | ht (32MB) | kt (18MB, reused k1 then k2) | zp (256B)
  __hip_bfloat16* xt = (__hip_bfloat16*)d_ws;
  __hip_bfloat16* ht = xt + (size_t)NB * NHW * NC;
  __hip_bfloat16* kt = ht + (size_t)NB * NHW * NC;
  float* zp = (float*)(kt + (size_t)NB * NC * NK);

  zero_zp<<<dim3(1), 64, 0, stream>>>(zp);
  prep_xt<<<dim3(64, 4, NB), 256, 0, stream>>>(x, xt);
  prep_kt<<<dim3(NB * NC), 256, 0, stream>>>(k1, kt);
  conv_gemm<1><<<dim3(256), 512, 0, stream>>>(xt, kt, nullptr, (const __hip_bfloat16*)zp, (void*)ht);
  prep_kt<<<dim3(NB * NC), 256, 0, stream>>>(k2, kt);
  conv_gemm<2><<<dim3(256), 512, 0, stream>>>(ht, kt, x, (const __hip_bfloat16*)zp, d_out);
}

// Round 4
// 245.046 us; speedup vs baseline: 1.1117x; 1.0203x over previous
//
#include <hip/hip_runtime.h>
#include <hip/hip_bf16.h>
#include <stdint.h>

typedef __attribute__((ext_vector_type(8))) short bf16x8;
typedef __attribute__((ext_vector_type(4))) float f32x4;
typedef __attribute__((address_space(1))) const void g_void;
typedef __attribute__((address_space(3))) void l_void;

#define NB 16
#define NC 256
#define NHW 4096
#define NK 2304  // 9*256
#define NT 72    // K-sub-tiles of 32

// ---------- prep: x NCHW f32 -> xt NHWC bf16 (tile transpose) ----------
__global__ __launch_bounds__(256) void prep_xt(const float* __restrict__ x,
                                               __hip_bfloat16* __restrict__ xt) {
  __shared__ float tile[64][65];
  const int b = blockIdx.z;
  const int cb = blockIdx.y << 6;
  const int pb = blockIdx.x << 6;
  const float* xs = x + ((size_t)(b * NC + cb) << 12) + pb;
#pragma unroll
  for (int k = 0; k < 16; ++k) {
    int idx = threadIdx.x + (k << 8);
    int c = idx >> 6, p = idx & 63;
    tile[p][c] = xs[((size_t)c << 12) + p];
  }
  __syncthreads();
  __hip_bfloat16* xd = xt + ((size_t)(b * NHW + pb) << 8) + cb;
#pragma unroll
  for (int k = 0; k < 16; ++k) {
    int idx = threadIdx.x + (k << 8);
    int p = idx >> 6, c = idx & 63;
    xd[(p << 8) + c] = __float2bfloat16(tile[p][c]);
  }
}

// ---------- prep: kernel [b][co][ci][3][3] f32 -> kt [b][co][s][ci] bf16 ----------
__global__ __launch_bounds__(256) void prep_kt(const float* __restrict__ kin,
                                               __hip_bfloat16* __restrict__ kt) {
  const size_t base = (size_t)blockIdx.x * NK;  // blockIdx.x = b*256+co
  const int ci = threadIdx.x;
  float v[9];
#pragma unroll
  for (int s = 0; s < 9; ++s) v[s] = kin[base + ci * 9 + s];
#pragma unroll
  for (int s = 0; s < 9; ++s) kt[base + (s << 8) + ci] = __float2bfloat16(v[s]);
}

__global__ void zero_zp(float* zp) { zp[threadIdx.x] = 0.f; }

// ---------- implicit-GEMM conv, 256x256 tile, BK=32 sub-tiles, 8-phase schedule ----
// PASS 1: A=image(M=pixel), B=kernel(N=co), out = ht bf16 NHWC (relu)
// PASS 2: A=kernel(M=co), B=image(N=pixel), out = fp32 NCHW (x + .., relu)
template <int PASS>
__global__ __launch_bounds__(512, 2) void conv_gemm(
    const __hip_bfloat16* __restrict__ img,  // [B][4096][256] bf16 (xt or ht)
    const __hip_bfloat16* __restrict__ kt,   // [B][256][2304] bf16
    const float* __restrict__ xres,          // pass2 residual (NCHW f32)
    const __hip_bfloat16* __restrict__ zp,   // 256B zero page
    void* __restrict__ outp) {
  // sub-tile t (K=32) lives in slot t&3 of each operand array.
  __shared__ short Ais[4][8192];  // image [256 rows][32 k], 64B rows, swizzled
  __shared__ short Kis[4][8192];  // kernel [256 rows][32 k]

  const int tid = threadIdx.x;
  const int lane = tid & 63;
  const int wid = tid >> 6;  // 0..7
  const int wm = wid >> 2;   // 0..1  (M half: 128 rows)
  const int wn = wid & 3;    // 0..3  (N quarter: 64 cols)

  // XCD-affine: XCD x owns logical blocks [32x,32x+32) = samples 2x,2x+1
  const int orig = blockIdx.x;
  const int g = ((orig & 7) << 5) + (orig >> 3);
  const int b = g >> 4;
  const int ptile = g & 15;
  const int pbase = ptile << 8;  // 256 pixels per tile

  const __hip_bfloat16* imgb = img + ((size_t)b << 20);
  const __hip_bfloat16* ktb = kt + (size_t)b * NC * NK;

  // staging geometry: instr i covers rows ((i*8+wid)*16 .. +16); lane -> row
  // +(lane>>2), HW slot lane&3; pre-swizzled source chunk c = slot^((row>>1)&3)
  const int c = (lane & 3) ^ ((lane >> 3) & 3);
  int hh[2], ww[2];
  const __hip_bfloat16* imgp[2];
  const __hip_bfloat16* ktp[2];
#pragma unroll
  for (int i = 0; i < 2; ++i) {
    const int m = (((i << 3) + wid) << 4) + (lane >> 2);  // tile row 0..255
    const int p = pbase + m;
    hh[i] = p >> 6;
    ww[i] = p & 63;
    imgp[i] = imgb + ((size_t)p << 8) + (c << 3);
    ktp[i] = ktb + (size_t)m * NK + (c << 3);
  }

  // fragment read offsets (shorts): row m, chunk lane>>4, swizzled
  int aoff[8], boff[4];
#pragma unroll
  for (int i = 0; i < 8; ++i) {
    const int m = (wm << 7) + (i << 4) + (lane & 15);
    aoff[i] = (m << 5) + ((((lane >> 4) ^ ((m >> 1) & 3))) << 3);
  }
#pragma unroll
  for (int j = 0; j < 4; ++j) {
    const int n = (wn << 6) + (j << 4) + (lane & 15);
    boff[j] = (n << 5) + ((((lane >> 4) ^ ((n >> 1) & 3))) << 3);
  }

  f32x4 acc[8][4];
#pragma unroll
  for (int i = 0; i < 8; ++i)
#pragma unroll
    for (int j = 0; j < 4; ++j) acc[i][j] = (f32x4){0.f, 0.f, 0.f, 0.f};

  auto stage_img = [&](int tn) {
    const int buf = tn & 3;
    const int s = tn >> 3;  // 0..8 = (kh,kw)
    const int dh = s / 3 - 1;
    const int dw = s % 3 - 1;
    const int doff = (((dh << 6) + dw) << 8) + ((tn & 7) << 5);
    const bool dummy = tn >= NT;
#pragma unroll
    for (int i = 0; i < 2; ++i) {
      const int h = hh[i] + dh;
      const int w = ww[i] + dw;
      const bool ok = !dummy && ((unsigned)h < 64u) && ((unsigned)w < 64u);
      const __hip_bfloat16* sa = ok ? imgp[i] + doff : zp;
      __builtin_amdgcn_global_load_lds((g_void*)sa,
                                       (l_void*)&Ais[buf][(((i << 3) + wid) << 9)], 16, 0, 0);
    }
  };
  auto stage_ker = [&](int tn) {
    const int buf = tn & 3;
    const int kof = ((tn >> 3) << 8) + ((tn & 7) << 5);
    const bool dummy = tn >= NT;
#pragma unroll
    for (int i = 0; i < 2; ++i) {
      const __hip_bfloat16* sb = dummy ? zp : ktp[i] + kof;
      __builtin_amdgcn_global_load_lds((g_void*)sb,
                                       (l_void*)&Kis[buf][(((i << 3) + wid) << 9)], 16, 0, 0);
    }
  };
  // M-operand array = A-side of the GEMM (rows), staged in phase alpha;
  // N-operand staged in phase beta.
  auto stageM = [&](int tn) { if (PASS == 1) stage_img(tn); else stage_ker(tn); };
  auto stageN = [&](int tn) { if (PASS == 1) stage_ker(tn); else stage_img(tn); };

  // prologue: N0,M0,N1,M1,N2,M2,N3 staged (14 loads); complete N0,M0.
  stageN(0); stageM(0); stageN(1); stageM(1); stageN(2); stageM(2); stageN(3);
  asm volatile("s_waitcnt vmcnt(10)" ::: "memory");
  __builtin_amdgcn_s_barrier();
  __builtin_amdgcn_sched_barrier(0);

#pragma unroll 1
  for (int t = 0; t < NT; ++t) {
    const int sl = t & 3;
    const short* At = (PASS == 1) ? Ais[sl] : Kis[sl];
    const short* Bt = (PASS == 1) ? Kis[sl] : Ais[sl];

    // ---------- phase alpha: 8 ds_read | stage M_{t+3} | 16 MFMA (m0-3) ----------
    bf16x8 fal[4], fb[4];
#pragma unroll
    for (int i = 0; i < 4; ++i) fal[i] = *(const bf16x8*)(At + aoff[i]);
#pragma unroll
    for (int j = 0; j < 4; ++j) fb[j] = *(const bf16x8*)(Bt + boff[j]);
    stageM(t + 3);
    __builtin_amdgcn_s_barrier();
    asm volatile("s_waitcnt lgkmcnt(0)" ::: "memory");
    __builtin_amdgcn_sched_barrier(0);
    __builtin_amdgcn_s_setprio(1);
#pragma unroll
    for (int i = 0; i < 4; ++i)
#pragma unroll
      for (int j = 0; j < 4; ++j)
        acc[i][j] = __builtin_amdgcn_mfma_f32_16x16x32_bf16(fal[i], fb[j], acc[i][j], 0, 0, 0);
    __builtin_amdgcn_s_setprio(0);
    __builtin_amdgcn_s_barrier();
    __builtin_amdgcn_sched_barrier(0);

    // ---------- phase beta: 4 ds_read | stage N_{t+4} | 16 MFMA (m4-7) ----------
    bf16x8 fah[4];
#pragma unroll
    for (int i = 0; i < 4; ++i) fah[i] = *(const bf16x8*)(At + aoff[4 + i]);
    stageN(t + 4);
    __builtin_amdgcn_s_barrier();
    asm volatile("s_waitcnt lgkmcnt(0)" ::: "memory");
    __builtin_amdgcn_sched_barrier(0);
    __builtin_amdgcn_s_setprio(1);
#pragma unroll
    for (int i = 0; i < 4; ++i)
#pragma unroll
      for (int j = 0; j < 4; ++j)
        acc[4 + i][j] = __builtin_amdgcn_mfma_f32_16x16x32_bf16(fah[i], fb[j], acc[4 + i][j], 0, 0, 0);
    __builtin_amdgcn_s_setprio(0);
    // counted wait: leaves N_{t+4}, M_{t+3}, N_{t+3} (3 tiles = 6 loads) in flight
    asm volatile("s_waitcnt vmcnt(6)" ::: "memory");
    __builtin_amdgcn_s_barrier();
    __builtin_amdgcn_sched_barrier(0);
  }
  asm volatile("s_waitcnt vmcnt(0)" ::: "memory");  // drain dummy stages
  __builtin_amdgcn_sched_barrier(0);

  const int lg = lane >> 4;
  const int ln = lane & 15;
  if (PASS == 1) {
    __hip_bfloat16* ho = (__hip_bfloat16*)outp;
#pragma unroll
    for (int i = 0; i < 8; ++i)
#pragma unroll
      for (int j = 0; j < 4; ++j)
#pragma unroll
        for (int r = 0; r < 4; ++r) {
          int pixel = pbase + (wm << 7) + (i << 4) + (lg << 2) + r;
          int co = (wn << 6) + (j << 4) + ln;
          float v = acc[i][j][r];
          v = v > 0.f ? v : 0.f;
          ho[((size_t)(b * NHW + pixel) << 8) + co] = __float2bfloat16(v);
        }
  } else {
    float* oo = (float*)outp;
#pragma unroll
    for (int i = 0; i < 8; ++i)
#pragma unroll
      for (int j = 0; j < 4; ++j)
#pragma unroll
        for (int r = 0; r < 4; ++r) {
          int co = (wm << 7) + (i << 4) + (lg << 2) + r;
          int pixel = pbase + (wn << 6) + (j << 4) + ln;
          size_t idx = ((size_t)(b * NC + co) << 12) + pixel;
          float v = acc[i][j][r] + xres[idx];
          oo[idx] = v > 0.f ? v : 0.f;
        }
  }
}

extern "C" void kernel_launch(void* const* d_in, const int* in_sizes, int n_in,
                              void* d_out, int out_size, void* d_ws, size_t ws_size,
                              hipStream_t stream) {
  const float* x = (const float*)d_in[0];
  const float* k1 = (const float*)d_in[1];
  const float* k2 = (const float*)d_in[2];

  // ws layout: xt (32MB) | ht (32MB) | kt (18MB, reused k1 then k2) | zp (256B)
  __hip_bfloat16* xt = (__hip_bfloat16*)d_ws;
  __hip_bfloat16* ht = xt + (size_t)NB * NHW * NC;
  __hip_bfloat16* kt = ht + (size_t)NB * NHW * NC;
  float* zp = (float*)(kt + (size_t)NB * NC * NK);

  zero_zp<<<dim3(1), 64, 0, stream>>>(zp);
  prep_xt<<<dim3(64, 4, NB), 256, 0, stream>>>(x, xt);
  prep_kt<<<dim3(NB * NC), 256, 0, stream>>>(k1, kt);
  conv_gemm<1><<<dim3(256), 512, 0, stream>>>(xt, kt, nullptr, (const __hip_bfloat16*)zp, (void*)ht);
  prep_kt<<<dim3(NB * NC), 256, 0, stream>>>(k2, kt);
  conv_gemm<2><<<dim3(256), 512, 0, stream>>>(ht, kt, x, (const __hip_bfloat16*)zp, d_out);
}